// Round 1
// baseline (547.498 us; speedup 1.0000x reference)
//
#include <hip/hip_runtime.h>
#include <math.h>

#define NTOK 32768          // B*S = 4*8192
#define HDIM 2048
#define K_SEL 22937         // int(0.7 * 32768)
#define EPS_F 1e-10f

// ---------------------------------------------------------------------------
// Kernel 1: per-token score (dot of 2048 floats), gumbel noise, sortable key,
// plus partial sums for the aux loss (sigmoid(score), score^2).
// One wave (64 lanes) per token; 4 tokens per 256-thread block.
// ---------------------------------------------------------------------------
__global__ __launch_bounds__(256) void score_kernel(
    const float* __restrict__ hidden,
    const float* __restrict__ u,
    const float* __restrict__ w,
    const float* __restrict__ b,
    unsigned int* __restrict__ keys,
    float* __restrict__ accum /* [0]=sum sigmoid, [1]=sum score^2 */)
{
    const int wave = threadIdx.x >> 6;
    const int lane = threadIdx.x & 63;
    const int token = blockIdx.x * 4 + wave;

    const float4* __restrict__ hrow = (const float4*)(hidden + (size_t)token * HDIM);
    const float4* __restrict__ w4   = (const float4*)w;

    float sum = 0.0f;
    #pragma unroll
    for (int j = 0; j < 8; ++j) {
        const int idx = j * 64 + lane;          // coalesced: lane-consecutive float4
        const float4 hv = hrow[idx];
        const float4 wv = w4[idx];
        sum += hv.x * wv.x + hv.y * wv.y + hv.z * wv.z + hv.w * wv.w;
    }
    // wave64 tree reduce
    #pragma unroll
    for (int off = 32; off > 0; off >>= 1)
        sum += __shfl_down(sum, off, 64);

    __shared__ float red_p[4];
    __shared__ float red_z[4];
    if (lane == 0) {
        const float score = sum + b[0];
        const float uu = u[token];
        // gumbel = -log(-log(u + eps) + eps); noisy = (score + gumbel) / 0.5
        const float g = -logf(-logf(uu + EPS_F) + EPS_F);
        const float noisy = (score + g) * 2.0f;
        // order-preserving uint32 key
        const unsigned int bits = __float_as_uint(noisy);
        const unsigned int key = (bits & 0x80000000u) ? ~bits : (bits | 0x80000000u);
        keys[token] = key;
        red_p[wave] = 1.0f / (1.0f + expf(-score));
        red_z[wave] = score * score;
    }
    __syncthreads();
    if (threadIdx.x == 0) {
        atomicAdd(&accum[0], red_p[0] + red_p[1] + red_p[2] + red_p[3]);
        atomicAdd(&accum[1], red_z[0] + red_z[1] + red_z[2] + red_z[3]);
    }
}

// ---------------------------------------------------------------------------
// Kernel 2: single workgroup, 1024 threads. Each thread owns 32 contiguous
// keys (in registers). 4-round radix select (256 bins) finds the k-th largest
// key tau and the count of ==tau elements to take (lowest-index-first, which
// matches jax.lax.top_k tie-breaking). Then writes the 0/1 mask and aux loss.
// All global reads of `keys` happen before the first barrier, all writes of
// `out` after the last one, so keys may alias out.
// ---------------------------------------------------------------------------
__global__ __launch_bounds__(1024) void select_kernel(
    const unsigned int* __restrict__ keys,
    const float* __restrict__ accum,
    float* __restrict__ out)
{
    __shared__ unsigned int hist[256];
    __shared__ unsigned int s_prefix;
    __shared__ unsigned int s_remaining;
    __shared__ unsigned int wtot[16];
    __shared__ unsigned int woff[16];

    const int t = threadIdx.x;
    const int lane = t & 63;
    const int wid = t >> 6;
    const int base = t * 32;

    unsigned int myk[32];
    #pragma unroll
    for (int j = 0; j < 32; ++j) myk[j] = keys[base + j];

    if (t == 0) { s_prefix = 0u; s_remaining = (unsigned int)K_SEL; }
    __syncthreads();

    unsigned int pmask = 0u;
    for (int r = 0; r < 4; ++r) {
        const int shift = 24 - r * 8;
        if (t < 256) hist[t] = 0u;
        __syncthreads();
        const unsigned int prefix = s_prefix;
        const unsigned int remaining = s_remaining;
        #pragma unroll
        for (int j = 0; j < 32; ++j) {
            const unsigned int kk = myk[j];
            if ((kk & pmask) == prefix)
                atomicAdd(&hist[(kk >> shift) & 255u], 1u);
        }
        __syncthreads();
        if (t == 0) {
            unsigned int cum = 0u;
            int d = 255;
            for (; d >= 0; --d) {
                const unsigned int c = hist[d];
                if (cum + c >= remaining) break;
                cum += c;
            }
            s_prefix = prefix | ((unsigned int)d << shift);
            s_remaining = remaining - cum;
        }
        pmask |= (0xFFu << shift);
        __syncthreads();
    }

    const unsigned int tau = s_prefix;
    const unsigned int needed = s_remaining;   // # of ==tau to take (lowest index first)

    // count equals in my contiguous chunk
    unsigned int ceq = 0u;
    #pragma unroll
    for (int j = 0; j < 32; ++j) ceq += (myk[j] == tau) ? 1u : 0u;

    // block-wide exclusive scan of per-chunk equal counts (index order == thread order)
    unsigned int v = ceq;
    #pragma unroll
    for (int off = 1; off < 64; off <<= 1) {
        const unsigned int n = __shfl_up(v, off, 64);
        if (lane >= off) v += n;
    }
    if (lane == 63) wtot[wid] = v;
    __syncthreads();
    if (t == 0) {
        unsigned int run = 0u;
        for (int i = 0; i < 16; ++i) { woff[i] = run; run += wtot[i]; }
    }
    __syncthreads();
    unsigned int rank = woff[wid] + (v - ceq);   // exclusive prefix of equals before my chunk

    #pragma unroll
    for (int j = 0; j < 32; ++j) {
        const unsigned int kk = myk[j];
        float val;
        if (kk > tau) {
            val = 1.0f;
        } else if (kk == tau) {
            val = (rank < needed) ? 1.0f : 0.0f;
            rank++;
        } else {
            val = 0.0f;
        }
        out[base + j] = val;
    }

    if (t == 0) {
        const float na = (float)NTOK;
        const float f = (float)K_SEL / na;
        const float p = accum[0] / na;
        const float z = accum[1] / na;
        const float dlb1 = f - 0.7f;
        const float dlb2 = p - 0.7f;
        const float lb = dlb1 * dlb1 + dlb2 * dlb2;
        out[NTOK] = 0.005f * lb + 5e-6f * z;
    }
}

extern "C" void kernel_launch(void* const* d_in, const int* in_sizes, int n_in,
                              void* d_out, int out_size, void* d_ws, size_t ws_size,
                              hipStream_t stream) {
    const float* hidden = (const float*)d_in[0];
    // d_in[1] = active_mask: all-true by construction, unused
    const float* u = (const float*)d_in[2];
    const float* w = (const float*)d_in[3];
    const float* b = (const float*)d_in[4];
    float* out = (float*)d_out;

    float* accum = (float*)d_ws;
    unsigned int* keys;
    if (ws_size >= 256 + (size_t)NTOK * sizeof(unsigned int)) {
        keys = (unsigned int*)((char*)d_ws + 256);
    } else {
        // fallback: stash keys in d_out; select_kernel reads all keys before
        // writing any output, so aliasing is safe.
        keys = (unsigned int*)d_out;
    }

    hipMemsetAsync(accum, 0, 2 * sizeof(float), stream);
    score_kernel<<<NTOK / 4, 256, 0, stream>>>(hidden, u, w, b, keys, accum);
    select_kernel<<<1, 1024, 0, stream>>>(keys, accum, out);
}

// Round 2
// 409.217 us; speedup vs baseline: 1.3379x; 1.3379x over previous
//
#include <hip/hip_runtime.h>
#include <math.h>

#define NTOK 32768          // B*S = 4*8192
#define HDIM 2048
#define K_SEL 22937         // int(0.7 * 32768)
#define EPS_F 1e-10f
#define NBLK 2048           // score blocks: 16 tokens per block, 4 per wave

// ---------------------------------------------------------------------------
// Kernel 1: per-token score (dot of 2048 floats), gumbel noise, sortable key.
// One wave handles 4 consecutive tokens; w preloaded into registers once.
// Per-block p/z partials to ws — NO global atomics (R1 showed 16384 contended
// atomics serialized the kernel to 223us).
// Dot-product order is bit-identical to the passing R1 kernel.
// ---------------------------------------------------------------------------
__global__ __launch_bounds__(256) void score_kernel(
    const float* __restrict__ hidden,
    const float* __restrict__ u,
    const float* __restrict__ w,
    const float* __restrict__ b,
    unsigned int* __restrict__ keys,
    float* __restrict__ pp,   // [NBLK] per-block sum of sigmoid(score)
    float* __restrict__ zz)   // [NBLK] per-block sum of score^2
{
    const int wave = threadIdx.x >> 6;
    const int lane = threadIdx.x & 63;
    const int tok0 = blockIdx.x * 16 + wave * 4;

    const float4* __restrict__ w4 = (const float4*)w;
    float4 wr[8];
    #pragma unroll
    for (int j = 0; j < 8; ++j) wr[j] = w4[j * 64 + lane];

    float p_acc = 0.0f, z_acc = 0.0f;
    #pragma unroll
    for (int t = 0; t < 4; ++t) {
        const int token = tok0 + t;
        const float4* __restrict__ hrow = (const float4*)(hidden + (size_t)token * HDIM);
        float sum = 0.0f;
        #pragma unroll
        for (int j = 0; j < 8; ++j) {
            const float4 hv = hrow[j * 64 + lane];   // coalesced 16B/lane
            sum += hv.x * wr[j].x + hv.y * wr[j].y + hv.z * wr[j].z + hv.w * wr[j].w;
        }
        #pragma unroll
        for (int off = 32; off > 0; off >>= 1)
            sum += __shfl_down(sum, off, 64);
        if (lane == 0) {
            const float score = sum + b[0];
            const float uu = u[token];
            const float g = -logf(-logf(uu + EPS_F) + EPS_F);
            const float noisy = (score + g) * 2.0f;     // /TEMP, TEMP=0.5
            const unsigned int bits = __float_as_uint(noisy);
            keys[token] = (bits & 0x80000000u) ? ~bits : (bits | 0x80000000u);
            p_acc += 1.0f / (1.0f + expf(-score));
            z_acc += score * score;
        }
    }

    __shared__ float red_p[4], red_z[4];
    if (lane == 0) { red_p[wave] = p_acc; red_z[wave] = z_acc; }
    __syncthreads();
    if (threadIdx.x == 0) {
        pp[blockIdx.x] = red_p[0] + red_p[1] + red_p[2] + red_p[3];
        zz[blockIdx.x] = red_z[0] + red_z[1] + red_z[2] + red_z[3];
    }
}

// ---------------------------------------------------------------------------
// Kernel 2: single workgroup, 1024 threads, 32 keys/thread in registers.
// 32-step bitwise binary search for the k-th largest key tau (block-wide
// count via shuffle reduce — no LDS atomics, no radix histograms), then
// lowest-index-first tie-break (matches jax.lax.top_k), mask write, and the
// aux-loss reduction over the 2048 per-block partials.
// All global reads of `keys` happen before any `out` write (aliasing-safe).
// ---------------------------------------------------------------------------
__global__ __launch_bounds__(1024) void select_kernel(
    const unsigned int* __restrict__ keys,
    const float* __restrict__ pp,
    const float* __restrict__ zz,
    float* __restrict__ out)
{
    __shared__ unsigned int wcnt[16];
    __shared__ float wredp[16], wredz[16];
    __shared__ unsigned int wtot[16], woff[16];

    const int t = threadIdx.x;
    const int lane = t & 63;
    const int wid = t >> 6;
    const int base = t * 32;

    unsigned int myk[32];
    #pragma unroll
    for (int j = 0; j < 32; ++j) myk[j] = keys[base + j];

    // ---- tau = k-th largest key: find max x with count(key >= x) >= K ----
    unsigned int tau = 0u;
    for (int bit = 31; bit >= 0; --bit) {
        const unsigned int cand = tau | (1u << bit);
        unsigned int c = 0u;
        #pragma unroll
        for (int j = 0; j < 32; ++j) c += (myk[j] >= cand) ? 1u : 0u;
        #pragma unroll
        for (int off = 32; off > 0; off >>= 1) c += __shfl_down(c, off, 64);
        if (lane == 0) wcnt[wid] = c;
        __syncthreads();
        unsigned int tot = 0u;
        #pragma unroll
        for (int i = 0; i < 16; ++i) tot += wcnt[i];
        if (tot >= (unsigned int)K_SEL) tau = cand;
        __syncthreads();   // protect wcnt reuse next iteration
    }

    // ---- how many ==tau to take (lowest index first) ----
    unsigned int cgt = 0u;
    #pragma unroll
    for (int j = 0; j < 32; ++j) cgt += (myk[j] > tau) ? 1u : 0u;
    unsigned int cg = cgt;
    #pragma unroll
    for (int off = 32; off > 0; off >>= 1) cg += __shfl_down(cg, off, 64);
    if (lane == 0) wcnt[wid] = cg;
    __syncthreads();
    unsigned int tot_gt = 0u;
    #pragma unroll
    for (int i = 0; i < 16; ++i) tot_gt += wcnt[i];
    const unsigned int needed = (unsigned int)K_SEL - tot_gt;

    // ---- exclusive scan (index order) of per-chunk equal counts ----
    unsigned int ceq = 0u;
    #pragma unroll
    for (int j = 0; j < 32; ++j) ceq += (myk[j] == tau) ? 1u : 0u;
    unsigned int v = ceq;
    #pragma unroll
    for (int off = 1; off < 64; off <<= 1) {
        const unsigned int n = __shfl_up(v, off, 64);
        if (lane >= off) v += n;
    }
    __syncthreads();
    if (lane == 63) wtot[wid] = v;
    __syncthreads();
    if (t == 0) {
        unsigned int run = 0u;
        for (int i = 0; i < 16; ++i) { woff[i] = run; run += wtot[i]; }
    }
    __syncthreads();
    unsigned int rank = woff[wid] + (v - ceq);

    // ---- write 0/1 mask ----
    #pragma unroll
    for (int j = 0; j < 32; ++j) {
        const unsigned int kk = myk[j];
        float val;
        if (kk > tau) {
            val = 1.0f;
        } else if (kk == tau) {
            val = (rank < needed) ? 1.0f : 0.0f;
            rank++;
        } else {
            val = 0.0f;
        }
        out[base + j] = val;
    }

    // ---- aux loss: reduce the 2048 per-block partials ----
    float lp = 0.0f, lz = 0.0f;
    if (t < 1024) {
        lp = pp[t] + pp[t + 1024];
        lz = zz[t] + zz[t + 1024];
    }
    #pragma unroll
    for (int off = 32; off > 0; off >>= 1) {
        lp += __shfl_down(lp, off, 64);
        lz += __shfl_down(lz, off, 64);
    }
    if (lane == 0) { wredp[wid] = lp; wredz[wid] = lz; }
    __syncthreads();
    if (t == 0) {
        float sp = 0.0f, sz = 0.0f;
        for (int i = 0; i < 16; ++i) { sp += wredp[i]; sz += wredz[i]; }
        const float na = (float)NTOK;
        const float f = (float)K_SEL / na;
        const float p = sp / na;
        const float z = sz / na;
        const float d1 = f - 0.7f;
        const float d2 = p - 0.7f;
        out[NTOK] = 0.005f * (d1 * d1 + d2 * d2) + 5e-6f * z;
    }
}

extern "C" void kernel_launch(void* const* d_in, const int* in_sizes, int n_in,
                              void* d_out, int out_size, void* d_ws, size_t ws_size,
                              hipStream_t stream) {
    const float* hidden = (const float*)d_in[0];
    // d_in[1] = active_mask: all-true by construction, unused
    const float* u = (const float*)d_in[2];
    const float* w = (const float*)d_in[3];
    const float* b = (const float*)d_in[4];
    float* out = (float*)d_out;

    const size_t KEYS_BYTES = (size_t)NTOK * sizeof(unsigned int);   // 128 KiB
    const size_t PART_BYTES = (size_t)NBLK * sizeof(float);          // 8 KiB

    unsigned int* keys;
    float *pp, *zz;
    if (ws_size >= KEYS_BYTES + 2 * PART_BYTES) {
        keys = (unsigned int*)d_ws;
        pp = (float*)((char*)d_ws + KEYS_BYTES);
        zz = pp + NBLK;
    } else {
        // fallback: stash keys in d_out (select reads all keys before writing
        // any output, so aliasing is safe); partials at ws start.
        keys = (unsigned int*)d_out;
        pp = (float*)d_ws;
        zz = pp + NBLK;
    }

    score_kernel<<<NBLK, 256, 0, stream>>>(hidden, u, w, b, keys, pp, zz);
    select_kernel<<<1, 1024, 0, stream>>>(keys, pp, zz, out);
}